// Round 3
// baseline (627.191 us; speedup 1.0000x reference)
//
#include <hip/hip_runtime.h>
#include <stdint.h>

#define DIN 4096
#define DOUT 4096
#define RNK 8
#define MROWS 8192   // B*S = 4*2048
#define NTILES 128   // DIN / 32

typedef unsigned short u16;
typedef __attribute__((ext_vector_type(8))) short short8;
typedef __attribute__((ext_vector_type(8))) unsigned short u16x8;
typedef __attribute__((ext_vector_type(4))) float f32x4;

// ---------- helpers ----------
__device__ __forceinline__ u16 f2bf(float f) {
    union { float f; uint32_t u; } v; v.f = f;
    uint32_t u = v.u;
    uint32_t r = (u + 0x7fffu + ((u >> 16) & 1u)) >> 16;   // RNE
    return (u16)r;
}

__device__ __forceinline__ void gl_lds16(const u16* g, u16* lds) {
    // direct global->LDS DMA, 16B per lane; LDS dest = wave-uniform base + lane*16
    __builtin_amdgcn_global_load_lds((const __attribute__((address_space(1))) unsigned int*)g,
                                     (__attribute__((address_space(3))) unsigned int*)lds,
                                     16, 0, 0);
}

// ---------- K1 (fused): normalize diag + Gram, one block ----------
// Raw S[i][j] = sum_d hra_u[d,i]*hra_u[d,j]; inv[i] = rsqrt(S[i][i]);
// G[i][j] = S[i][j]*inv[i]*inv[j]; Un[i][d] = hra_u[d][i]*inv[i].
__global__ __launch_bounds__(1024) void k_prep(const float* __restrict__ hra_u,
                                               float* __restrict__ Un,
                                               float* __restrict__ G) {
    const int t = threadIdx.x;
    float s[64];
    #pragma unroll
    for (int k = 0; k < 64; k++) s[k] = 0.f;
    for (int d = t; d < DIN; d += 1024) {
        float4 p = *(const float4*)(hra_u + d * 8);
        float4 q = *(const float4*)(hra_u + d * 8 + 4);
        float v[8] = {p.x, p.y, p.z, p.w, q.x, q.y, q.z, q.w};
        #pragma unroll
        for (int i = 0; i < 8; i++)
            #pragma unroll
            for (int j = 0; j < 8; j++)
                s[i * 8 + j] += v[i] * v[j];
    }
    #pragma unroll
    for (int k = 0; k < 64; k++)
        for (int off = 32; off; off >>= 1)
            s[k] += __shfl_down(s[k], off, 64);
    __shared__ float red[16][64];
    __shared__ float Sg[64];
    __shared__ float inv[8];
    if ((t & 63) == 0) {
        #pragma unroll
        for (int k = 0; k < 64; k++) red[t >> 6][k] = s[k];
    }
    __syncthreads();
    if (t < 64) {
        float tot = 0.f;
        #pragma unroll
        for (int w = 0; w < 16; w++) tot += red[w][t];
        Sg[t] = tot;
    }
    __syncthreads();
    if (t < 8) inv[t] = rsqrtf(Sg[t * 8 + t]);
    __syncthreads();
    if (t < 64) G[t] = Sg[t] * inv[t >> 3] * inv[t & 7];
    float iv[8];
    #pragma unroll
    for (int i = 0; i < 8; i++) iv[i] = inv[i];
    for (int d = t; d < DIN; d += 1024) {
        float4 p = *(const float4*)(hra_u + d * 8);
        float4 q = *(const float4*)(hra_u + d * 8 + 4);
        Un[0 * DIN + d] = p.x * iv[0];
        Un[1 * DIN + d] = p.y * iv[1];
        Un[2 * DIN + d] = p.z * iv[2];
        Un[3 * DIN + d] = p.w * iv[3];
        Un[4 * DIN + d] = q.x * iv[4];
        Un[5 * DIN + d] = q.y * iv[5];
        Un[6 * DIN + d] = q.z * iv[6];
        Un[7 * DIN + d] = q.w * iv[7];
    }
}

// ---------- K2 (rewritten): 16 rows per block, Un staged in LDS, W row held in regs ----------
// Per row o: v_i = W[o,:].Un_i -> triangular solve y -> W' = W - sum_i y_i Un_i, cast bf16.
// W read ONCE (registers reused for the update pass); Un L2 traffic 256*131KB = 33 MB.
__global__ __launch_bounds__(512) void k_wy_build(const float* __restrict__ W,
                                                  const float* __restrict__ Un,
                                                  const float* __restrict__ G,
                                                  u16* __restrict__ Wb) {
    __shared__ float Us[RNK * DIN];   // 131072 B
    const int t = threadIdx.x;
    #pragma unroll
    for (int j = 0; j < 16; j++) {
        const int c = t + 512 * j;    // float4 id, 8192 total
        *(float4*)&Us[c * 4] = *(const float4*)&Un[c * 4];
    }
    __syncthreads();
    const int wv = t >> 6, l = t & 63;
    #pragma unroll 1
    for (int rr = 0; rr < 2; rr++) {
        const int row = blockIdx.x * 16 + wv * 2 + rr;
        const float* wrow = W + (size_t)row * DIN;
        float4 wc[16];
        float acc[RNK] = {};
        #pragma unroll
        for (int j = 0; j < 16; j++) {
            const int c = l + 64 * j;
            wc[j] = *(const float4*)(wrow + c * 4);
            #pragma unroll
            for (int i = 0; i < RNK; i++) {
                float4 uv = *(const float4*)&Us[(i * 1024 + c) * 4];
                acc[i] += wc[j].x * uv.x + wc[j].y * uv.y + wc[j].z * uv.z + wc[j].w * uv.w;
            }
        }
        #pragma unroll
        for (int i = 0; i < RNK; i++)
            for (int off = 32; off; off >>= 1)
                acc[i] += __shfl_down(acc[i], off, 64);
        float yv[RNK];
        if (l == 0) {
            #pragma unroll
            for (int i = 0; i < RNK; i++) {
                float s2 = acc[i];
                for (int j = 0; j < i; j++) s2 -= yv[j] * G[j * RNK + i];
                yv[i] = 2.f * s2;
            }
        }
        #pragma unroll
        for (int i = 0; i < RNK; i++) yv[i] = __shfl(yv[i], 0, 64);
        #pragma unroll
        for (int j = 0; j < 16; j++) {
            const int c = l + 64 * j;
            float4 r = wc[j];
            #pragma unroll
            for (int i = 0; i < RNK; i++) {
                float4 uv = *(const float4*)&Us[(i * 1024 + c) * 4];
                r.x -= yv[i] * uv.x; r.y -= yv[i] * uv.y;
                r.z -= yv[i] * uv.z; r.w -= yv[i] * uv.w;
            }
            ushort4 ov;
            ov.x = f2bf(r.x); ov.y = f2bf(r.y); ov.z = f2bf(r.z); ov.w = f2bf(r.w);
            *(ushort4*)(Wb + (size_t)row * DIN + c * 4) = ov;
        }
    }
}

// ---------- K3: cast x (fp32) -> bf16, grid-stride ----------
__global__ __launch_bounds__(256) void k_cast_x(const float* __restrict__ x,
                                                u16* __restrict__ xb) {
    const size_t total = (size_t)MROWS * DIN / 8;
    for (size_t idx = (size_t)blockIdx.x * 256 + threadIdx.x; idx < total;
         idx += (size_t)2048 * 256) {
        float4 a = *(const float4*)(x + idx * 8);
        float4 b = *(const float4*)(x + idx * 8 + 4);
        u16x8 o;
        o[0] = f2bf(a.x); o[1] = f2bf(a.y); o[2] = f2bf(a.z); o[3] = f2bf(a.w);
        o[4] = f2bf(b.x); o[5] = f2bf(b.y); o[6] = f2bf(b.z); o[7] = f2bf(b.w);
        *(u16x8*)(xb + idx * 8) = o;
    }
}

// ---------- K4: main GEMM  C[M,N] = A[M,K] @ B[N,K]^T + bias ----------
// 256x256 tile, 512 thr = 8 waves (2Mx4N), per-wave 128x64 (acc[8][4]). BK=32, ring-4 LDS.
// SKEWED fragment pipeline: frags are ds_read one window BEFORE their MFMA window, so the
// compiler's automatic (counted) lgkm waits are satisfied by the time of use -> LDS pipe
// drains UNDER the MFMA windows (no lgkmcnt(0) serialization). Windows per tile:
//   R0: read a1(tile kt) | stage A(kt+3) | barrier
//   M0: MFMA a0 x bcur   | vmcnt(6)      | barrier   <- tile kt+1 landed for ALL waves
//   R1: read a0',bnext (tile kt+1) | stage B(kt+3) | barrier
//   M1: MFMA a1 x bcur   | barrier
// vmcnt(6): issued 14+4kt, need tiles 0..kt+1 = 4kt+8 done -> 6 newest may remain. Tail
// stages wrap modulo NTILES to keep the count uniform (redundant loads, never consumed).
// B-frags double-buffered (bA/bB) via tile-parity unroll (static indexing, no scratch).
__global__ __launch_bounds__(512, 2) void k_gemm(const u16* __restrict__ A,   // xb [M][K]
                                                 const u16* __restrict__ B,   // Wb [N][K]
                                                 const float* __restrict__ bias,
                                                 float* __restrict__ C) {
    __shared__ u16 sm[65536];   // 128 KiB: [buf 0..3][A:8192 | B:8192] u16

    const int t = threadIdx.x;
    const int w = t >> 6, l = t & 63;
    const int bm = blockIdx.x & 31;   // M/256 = 32
    const int bn = blockIdx.x >> 5;   // N/256 = 16
    const int wm = w >> 2, wn = w & 3;

    const int quad = l >> 4, lane16 = l & 15;

    // staging source (inverse-swizzled global address), per lane — verified round 2
    const int lc   = (l & 7) ^ (l >> 3);
    const int prow = lc >> 2;
    const int kch  = lc & 3;
    const int rA0  = (2 * w) * 16 + 2 * (l >> 3) + prow;
    const u16* agp0 = A + (size_t)(bm * 256 + rA0) * DIN + kch * 8;
    const u16* agp1 = agp0 + (size_t)16 * DIN;
    const u16* bgp0 = B + (size_t)(bn * 256 + rA0) * DIN + kch * 8;
    const u16* bgp1 = bgp0 + (size_t)16 * DIN;
    const int ldso0 = (2 * w) * 512;
    const int ldso1 = (2 * w + 1) * 512;

    // ds_read addressing (swizzled) — verified round 2 (0 bank conflicts)
    const int pA    = (((lane16 & 1) * 4 + quad) ^ ((lane16 >> 1) & 7)) * 8;
    const int a_off = (wm * 64 + (lane16 >> 1)) * 64 + pA;
    const int b_off = (wn * 32 + (lane16 >> 1)) * 64 + pA;

    f32x4 acc[8][4] = {};
    short8 a0[4], a1[4], bA[4], bB[4];

    // ---- prologue: stage tiles 0,1,2; preload tile-0 phase-0 frags ----
    #pragma unroll
    for (int tt = 0; tt < 3; tt++) {
        u16* Asw = sm + tt * 16384;
        const int kc = tt * 32;
        gl_lds16(agp0 + kc, Asw + ldso0);
        gl_lds16(agp1 + kc, Asw + ldso1);
        gl_lds16(bgp0 + kc, Asw + 8192 + ldso0);
        gl_lds16(bgp1 + kc, Asw + 8192 + ldso1);
    }
    asm volatile("s_waitcnt vmcnt(8)" ::: "memory");   // own tile-0 stores landed
    __builtin_amdgcn_s_barrier();                      // ... for ALL waves
    #pragma unroll
    for (int mt = 0; mt < 4; mt++) a0[mt] = *(const short8*)&sm[a_off + (mt * 8) * 64];
    #pragma unroll
    for (int nt = 0; nt < 4; nt++) bA[nt] = *(const short8*)&sm[8192 + b_off + (nt * 8) * 64];

#define TILE_BODY(KT, BC, BN)                                                         \
    {                                                                                 \
        u16* As_c = sm + ((KT) & 3) * 16384;                                          \
        u16* As_n = sm + (((KT) + 1) & 3) * 16384;                                    \
        u16* As_s = sm + (((KT) + 3) & 3) * 16384;                                    \
        const int kc3 = (((KT) + 3) & (NTILES - 1)) * 32;                             \
        /* R0: phase-1 frags of current tile + A-stage */                             \
        _Pragma("unroll")                                                             \
        for (int mt = 0; mt < 4; mt++)                                                \
            a1[mt] = *(const short8*)&As_c[a_off + (32 + mt * 8) * 64];               \
        gl_lds16(agp0 + kc3, As_s + ldso0);                                           \
        gl_lds16(agp1 + kc3, As_s + ldso1);                                           \
        __builtin_amdgcn_sched_barrier(0);                                            \
        __builtin_amdgcn_s_barrier();                                                 \
        /* M0 */                                                                      \
        __builtin_amdgcn_s_setprio(1);                                                \
        _Pragma("unroll")                                                             \
        for (int mt = 0; mt < 4; mt++)                                                \
            _Pragma("unroll")                                                         \
            for (int nt = 0; nt < 4; nt++)                                            \
                acc[mt][nt] = __builtin_amdgcn_mfma_f32_16x16x32_bf16(                \
                    a0[mt], BC[nt], acc[mt][nt], 0, 0, 0);                            \
        __builtin_amdgcn_s_setprio(0);                                                \
        asm volatile("s_waitcnt vmcnt(6)" ::: "memory");                              \
        __builtin_amdgcn_s_barrier();                                                 \
        /* R1: next tile's phase-0 frags + B-stage */                                 \
        _Pragma("unroll")                                                             \
        for (int mt = 0; mt < 4; mt++)                                                \
            a0[mt] = *(const short8*)&As_n[a_off + (mt * 8) * 64];                    \
        _Pragma("unroll")                                                             \
        for (int nt = 0; nt < 4; nt++)                                                \
            BN[nt] = *(const short8*)&As_n[8192 + b_off + (nt * 8) * 64];             \
        gl_lds16(bgp0 + kc3, As_s + 8192 + ldso0);                                    \
        gl_lds16(bgp1 + kc3, As_s + 8192 + ldso1);                                    \
        __builtin_amdgcn_sched_barrier(0);                                            \
        __builtin_amdgcn_s_barrier();                                                 \
        /* M1 */                                                                      \
        __builtin_amdgcn_s_setprio(1);                                                \
        _Pragma("unroll")                                                             \
        for (int mt = 0; mt < 4; mt++)                                                \
            _Pragma("unroll")                                                         \
            for (int nt = 0; nt < 4; nt++)                                            \
                acc[4 + mt][nt] = __builtin_amdgcn_mfma_f32_16x16x32_bf16(            \
                    a1[mt], BC[nt], acc[4 + mt][nt], 0, 0, 0);                        \
        __builtin_amdgcn_s_setprio(0);                                                \
        __builtin_amdgcn_s_barrier();                                                 \
    }

    #pragma unroll 1
    for (int kt2 = 0; kt2 < NTILES; kt2 += 2) {
        TILE_BODY(kt2,     bA, bB)
        TILE_BODY(kt2 + 1, bB, bA)
    }
#undef TILE_BODY

    // ---- epilogue: D layout col=lane&15, row=quad*4+reg ----
    const int col0 = bn * 256 + wn * 64 + lane16;
    const int row00 = bm * 256 + wm * 128 + quad * 4;
    float bv[4];
    #pragma unroll
    for (int nt = 0; nt < 4; nt++) bv[nt] = bias[col0 + nt * 16];
    #pragma unroll
    for (int half = 0; half < 2; half++) {
        #pragma unroll
        for (int mt = 0; mt < 4; mt++) {
            const int row0 = row00 + half * 64 + mt * 16;
            #pragma unroll
            for (int nt = 0; nt < 4; nt++) {
                #pragma unroll
                for (int rr = 0; rr < 4; rr++) {
                    C[(size_t)(row0 + rr) * DOUT + col0 + nt * 16] =
                        acc[half * 4 + mt][nt][rr] + bv[nt];
                }
            }
        }
    }
}

extern "C" void kernel_launch(void* const* d_in, const int* in_sizes, int n_in,
                              void* d_out, int out_size, void* d_ws, size_t ws_size,
                              hipStream_t stream) {
    const float* x     = (const float*)d_in[0];   // [4,2048,4096]
    const float* hra_u = (const float*)d_in[1];   // [4096,8]
    const float* W     = (const float*)d_in[2];   // [4096,4096]
    const float* bias  = (const float*)d_in[3];   // [4096]
    float* out = (float*)d_out;

    char* ws = (char*)d_ws;
    float* Un = (float*)(ws);                         // 8*4096*4   = 131072 B
    float* G  = (float*)(ws + 131072);                // 64*4       = 256 B
    u16*   Wb = (u16*)(ws + 524288);                  // 4096*4096*2 = 33554432 B
    u16*   xb = (u16*)(ws + 524288 + 33554432);       // 8192*4096*2 = 67108864 B

    k_prep<<<1, 1024, 0, stream>>>(hra_u, Un, G);
    k_wy_build<<<DOUT / 16, 512, 0, stream>>>(W, Un, G, Wb);
    k_cast_x<<<2048, 256, 0, stream>>>(x, xb);
    k_gemm<<<(MROWS / 256) * (DOUT / 256), 512, 0, stream>>>(xb, Wb, bias, out);
}

// Round 4
// 545.271 us; speedup vs baseline: 1.1502x; 1.1502x over previous
//
#include <hip/hip_runtime.h>
#include <stdint.h>

#define DIN 4096
#define DOUT 4096
#define RNK 8
#define MROWS 8192   // B*S = 4*2048
#define NTILES 128   // DIN / 32

typedef unsigned short u16;
typedef __attribute__((ext_vector_type(8))) short short8;
typedef __attribute__((ext_vector_type(8))) unsigned short u16x8;
typedef __attribute__((ext_vector_type(4))) float f32x4;

// ---------- helpers ----------
__device__ __forceinline__ u16 f2bf(float f) {
    union { float f; uint32_t u; } v; v.f = f;
    uint32_t u = v.u;
    uint32_t r = (u + 0x7fffu + ((u >> 16) & 1u)) >> 16;   // RNE
    return (u16)r;
}

__device__ __forceinline__ void gl_lds16(const u16* g, u16* lds) {
    // direct global->LDS DMA, 16B per lane; LDS dest = wave-uniform base + lane*16
    __builtin_amdgcn_global_load_lds((const __attribute__((address_space(1))) unsigned int*)g,
                                     (__attribute__((address_space(3))) unsigned int*)lds,
                                     16, 0, 0);
}

// ---------- K1 (fused): normalize diag + Gram, one block ----------
__global__ __launch_bounds__(1024) void k_prep(const float* __restrict__ hra_u,
                                               float* __restrict__ Un,
                                               float* __restrict__ G) {
    const int t = threadIdx.x;
    float s[64];
    #pragma unroll
    for (int k = 0; k < 64; k++) s[k] = 0.f;
    for (int d = t; d < DIN; d += 1024) {
        float4 p = *(const float4*)(hra_u + d * 8);
        float4 q = *(const float4*)(hra_u + d * 8 + 4);
        float v[8] = {p.x, p.y, p.z, p.w, q.x, q.y, q.z, q.w};
        #pragma unroll
        for (int i = 0; i < 8; i++)
            #pragma unroll
            for (int j = 0; j < 8; j++)
                s[i * 8 + j] += v[i] * v[j];
    }
    #pragma unroll
    for (int k = 0; k < 64; k++)
        for (int off = 32; off; off >>= 1)
            s[k] += __shfl_down(s[k], off, 64);
    __shared__ float red[16][64];
    __shared__ float Sg[64];
    __shared__ float inv[8];
    if ((t & 63) == 0) {
        #pragma unroll
        for (int k = 0; k < 64; k++) red[t >> 6][k] = s[k];
    }
    __syncthreads();
    if (t < 64) {
        float tot = 0.f;
        #pragma unroll
        for (int w = 0; w < 16; w++) tot += red[w][t];
        Sg[t] = tot;
    }
    __syncthreads();
    if (t < 8) inv[t] = rsqrtf(Sg[t * 8 + t]);
    __syncthreads();
    if (t < 64) G[t] = Sg[t] * inv[t >> 3] * inv[t & 7];
    float iv[8];
    #pragma unroll
    for (int i = 0; i < 8; i++) iv[i] = inv[i];
    for (int d = t; d < DIN; d += 1024) {
        float4 p = *(const float4*)(hra_u + d * 8);
        float4 q = *(const float4*)(hra_u + d * 8 + 4);
        Un[0 * DIN + d] = p.x * iv[0];
        Un[1 * DIN + d] = p.y * iv[1];
        Un[2 * DIN + d] = p.z * iv[2];
        Un[3 * DIN + d] = p.w * iv[3];
        Un[4 * DIN + d] = q.x * iv[4];
        Un[5 * DIN + d] = q.y * iv[5];
        Un[6 * DIN + d] = q.z * iv[6];
        Un[7 * DIN + d] = q.w * iv[7];
    }
}

// ---------- K2: round-2 version (reverted — measured-good): one row per block ----------
__global__ __launch_bounds__(256) void k_wy_build(const float* __restrict__ W,
                                                  const float* __restrict__ Un,
                                                  const float* __restrict__ G,
                                                  u16* __restrict__ Wb) {
    const int o = blockIdx.x;
    const int t = threadIdx.x;
    const float* wrow = W + (size_t)o * DIN;

    float4 wv[4];
    float acc[RNK] = {};
    #pragma unroll
    for (int j = 0; j < 4; j++) {
        const int c = t + j * 256;              // float4 chunk id
        wv[j] = *(const float4*)(wrow + c * 4);
        #pragma unroll
        for (int i = 0; i < RNK; i++) {
            float4 uv = *(const float4*)(Un + i * DIN + c * 4);
            acc[i] += wv[j].x * uv.x + wv[j].y * uv.y + wv[j].z * uv.z + wv[j].w * uv.w;
        }
    }
    #pragma unroll
    for (int i = 0; i < RNK; i++)
        for (int off = 32; off; off >>= 1)
            acc[i] += __shfl_down(acc[i], off, 64);
    __shared__ float red[4][RNK];
    __shared__ float ysh[RNK];
    if ((t & 63) == 0) {
        #pragma unroll
        for (int i = 0; i < RNK; i++) red[t >> 6][i] = acc[i];
    }
    __syncthreads();
    if (t == 0) {
        float y[RNK];
        #pragma unroll
        for (int i = 0; i < RNK; i++) {
            float s = red[0][i] + red[1][i] + red[2][i] + red[3][i];
            for (int j = 0; j < i; j++) s -= y[j] * G[j * RNK + i];
            y[i] = 2.f * s;
            ysh[i] = y[i];
        }
    }
    __syncthreads();
    float y[RNK];
    #pragma unroll
    for (int i = 0; i < RNK; i++) y[i] = ysh[i];

    #pragma unroll
    for (int j = 0; j < 4; j++) {
        const int c = t + j * 256;
        float4 r = wv[j];
        #pragma unroll
        for (int i = 0; i < RNK; i++) {
            float4 uv = *(const float4*)(Un + i * DIN + c * 4);   // L2-hot re-read
            r.x -= y[i] * uv.x; r.y -= y[i] * uv.y;
            r.z -= y[i] * uv.z; r.w -= y[i] * uv.w;
        }
        ushort4 ov;
        ov.x = f2bf(r.x); ov.y = f2bf(r.y); ov.z = f2bf(r.z); ov.w = f2bf(r.w);
        *(ushort4*)(Wb + (size_t)o * DIN + c * 4) = ov;
    }
}

// ---------- K3: cast x (fp32) -> bf16, grid-stride ----------
__global__ __launch_bounds__(256) void k_cast_x(const float* __restrict__ x,
                                                u16* __restrict__ xb) {
    const size_t total = (size_t)MROWS * DIN / 8;
    for (size_t idx = (size_t)blockIdx.x * 256 + threadIdx.x; idx < total;
         idx += (size_t)2048 * 256) {
        float4 a = *(const float4*)(x + idx * 8);
        float4 b = *(const float4*)(x + idx * 8 + 4);
        u16x8 o;
        o[0] = f2bf(a.x); o[1] = f2bf(a.y); o[2] = f2bf(a.z); o[3] = f2bf(a.w);
        o[4] = f2bf(b.x); o[5] = f2bf(b.y); o[6] = f2bf(b.z); o[7] = f2bf(b.w);
        *(u16x8*)(xb + idx * 8) = o;
    }
}

// ---------- K4: main GEMM  C[M,N] = A[M,K] @ B[N,K]^T + bias ----------
// 256x256 tile, 512 thr = 8 waves (2Mx4N), per-wave 128x64 (acc[8][4]). BK=32, ring-4 LDS.
// ONE barrier per K-tile (was 4). Skewed frag reads (consumed one region after issue) make
// all lgkm waits counted-and-satisfied; with only one barrier the inter-barrier region
// {R1,M1,R0,M0} = 32 MFMA + 12 ds_read + 4 gl_lds holds only true register deps, so the
// LDS pipe drains UNDER the MFMA stream and the 2 waves/SIMD drift within the region.
// Hazard ledger (re-verified):
//  - stage A(kt+3)@R0(kt) -> buf[(kt-1)&3]A: last readers a1@R0(kt-1) / a0'@R1(kt-2),
//    both before bar(kt-1); write issued after it.  (1 barrier between)
//  - stage B(kt+3)@R1(kt) -> buf[(kt-1)&3]B: last reader b'@R1(kt-2), 2 barriers back.
//  - reads after bar(kt) need tiles <= kt+1 landed: issued 14+4kt, vmcnt(6) completes
//    through tile kt+1's B-stage exactly.
//  - ds_reads pending at a barrier are separated from it by a 16-MFMA burst (~300cy),
//    incoming DMA lands >=200cy after the barrier -> no LDS read/DMA-write race.
// Post-loop vmcnt(0): tail wrap-stages must not outlive the block's LDS allocation.
__global__ __launch_bounds__(512, 2) void k_gemm(const u16* __restrict__ A,   // xb [M][K]
                                                 const u16* __restrict__ B,   // Wb [N][K]
                                                 const float* __restrict__ bias,
                                                 float* __restrict__ C) {
    __shared__ u16 sm[65536];   // 128 KiB: [buf 0..3][A:8192 | B:8192] u16

    const int t = threadIdx.x;
    const int w = t >> 6, l = t & 63;
    const int bm = blockIdx.x & 31;   // M/256 = 32
    const int bn = blockIdx.x >> 5;   // N/256 = 16
    const int wm = w >> 2, wn = w & 3;

    const int quad = l >> 4, lane16 = l & 15;

    // staging source (inverse-swizzled global address), per lane — verified round 2
    const int lc   = (l & 7) ^ (l >> 3);
    const int prow = lc >> 2;
    const int kch  = lc & 3;
    const int rA0  = (2 * w) * 16 + 2 * (l >> 3) + prow;
    const u16* agp0 = A + (size_t)(bm * 256 + rA0) * DIN + kch * 8;
    const u16* agp1 = agp0 + (size_t)16 * DIN;
    const u16* bgp0 = B + (size_t)(bn * 256 + rA0) * DIN + kch * 8;
    const u16* bgp1 = bgp0 + (size_t)16 * DIN;
    const int ldso0 = (2 * w) * 512;
    const int ldso1 = (2 * w + 1) * 512;

    // ds_read addressing (swizzled) — verified round 2 (0 bank conflicts)
    const int pA    = (((lane16 & 1) * 4 + quad) ^ ((lane16 >> 1) & 7)) * 8;
    const int a_off = (wm * 64 + (lane16 >> 1)) * 64 + pA;
    const int b_off = (wn * 32 + (lane16 >> 1)) * 64 + pA;

    f32x4 acc[8][4] = {};
    short8 a0[4], a1[4], bA[4], bB[4];

    // ---- prologue: stage tiles 0,1,2; preload tile-0 phase-0 frags ----
    #pragma unroll
    for (int tt = 0; tt < 3; tt++) {
        u16* Asw = sm + tt * 16384;
        const int kc = tt * 32;
        gl_lds16(agp0 + kc, Asw + ldso0);
        gl_lds16(agp1 + kc, Asw + ldso1);
        gl_lds16(bgp0 + kc, Asw + 8192 + ldso0);
        gl_lds16(bgp1 + kc, Asw + 8192 + ldso1);
    }
    asm volatile("s_waitcnt vmcnt(8)" ::: "memory");   // tile-0 stores landed
    __builtin_amdgcn_s_barrier();                      // ... for ALL waves
    #pragma unroll
    for (int mt = 0; mt < 4; mt++) a0[mt] = *(const short8*)&sm[a_off + (mt * 8) * 64];
    #pragma unroll
    for (int nt = 0; nt < 4; nt++) bA[nt] = *(const short8*)&sm[8192 + b_off + (nt * 8) * 64];

#define TILE_BODY(KT, BC, BN)                                                         \
    {                                                                                 \
        u16* As_c = sm + ((KT) & 3) * 16384;                                          \
        u16* As_n = sm + (((KT) + 1) & 3) * 16384;                                    \
        u16* As_s = sm + (((KT) + 3) & 3) * 16384;                                    \
        const int kc3 = (((KT) + 3) & (NTILES - 1)) * 32;                             \
        /* R0: phase-1 frags of current tile + A-stage */                             \
        _Pragma("unroll")                                                             \
        for (int mt = 0; mt < 4; mt++)                                                \
            a1[mt] = *(const short8*)&As_c[a_off + (32 + mt * 8) * 64];               \
        gl_lds16(agp0 + kc3, As_s + ldso0);                                           \
        gl_lds16(agp1 + kc3, As_s + ldso1);                                           \
        __builtin_amdgcn_sched_barrier(0);                                            \
        /* M0 (no preceding barrier — R0 reads/writes proven hazard-free) */          \
        __builtin_amdgcn_s_setprio(1);                                                \
        _Pragma("unroll")                                                             \
        for (int mt = 0; mt < 4; mt++)                                                \
            _Pragma("unroll")                                                         \
            for (int nt = 0; nt < 4; nt++)                                            \
                acc[mt][nt] = __builtin_amdgcn_mfma_f32_16x16x32_bf16(                \
                    a0[mt], BC[nt], acc[mt][nt], 0, 0, 0);                            \
        __builtin_amdgcn_s_setprio(0);                                                \
        asm volatile("s_waitcnt vmcnt(6)" ::: "memory");                              \
        __builtin_amdgcn_s_barrier();        /* THE one barrier of tile KT */         \
        /* R1: next tile's phase-0 frags + B-stage */                                 \
        _Pragma("unroll")                                                             \
        for (int mt = 0; mt < 4; mt++)                                                \
            a0[mt] = *(const short8*)&As_n[a_off + (mt * 8) * 64];                    \
        _Pragma("unroll")                                                             \
        for (int nt = 0; nt < 4; nt++)                                                \
            BN[nt] = *(const short8*)&As_n[8192 + b_off + (nt * 8) * 64];             \
        gl_lds16(bgp0 + kc3, As_s + 8192 + ldso0);                                    \
        gl_lds16(bgp1 + kc3, As_s + 8192 + ldso1);                                    \
        __builtin_amdgcn_sched_barrier(0);                                            \
        /* M1 (no trailing barrier) */                                                \
        __builtin_amdgcn_s_setprio(1);                                                \
        _Pragma("unroll")                                                             \
        for (int mt = 0; mt < 4; mt++)                                                \
            _Pragma("unroll")                                                         \
            for (int nt = 0; nt < 4; nt++)                                            \
                acc[4 + mt][nt] = __builtin_amdgcn_mfma_f32_16x16x32_bf16(            \
                    a1[mt], BC[nt], acc[4 + mt][nt], 0, 0, 0);                        \
        __builtin_amdgcn_s_setprio(0);                                                \
    }

    #pragma unroll 1
    for (int kt2 = 0; kt2 < NTILES; kt2 += 2) {
        TILE_BODY(kt2,     bA, bB)
        TILE_BODY(kt2 + 1, bB, bA)
    }
#undef TILE_BODY

    asm volatile("s_waitcnt vmcnt(0)" ::: "memory");   // drain tail wrap-stages

    // ---- epilogue: D layout col=lane&15, row=quad*4+reg ----
    const int col0 = bn * 256 + wn * 64 + lane16;
    const int row00 = bm * 256 + wm * 128 + quad * 4;
    float bv[4];
    #pragma unroll
    for (int nt = 0; nt < 4; nt++) bv[nt] = bias[col0 + nt * 16];
    #pragma unroll
    for (int half = 0; half < 2; half++) {
        #pragma unroll
        for (int mt = 0; mt < 4; mt++) {
            const int row0 = row00 + half * 64 + mt * 16;
            #pragma unroll
            for (int nt = 0; nt < 4; nt++) {
                #pragma unroll
                for (int rr = 0; rr < 4; rr++) {
                    C[(size_t)(row0 + rr) * DOUT + col0 + nt * 16] =
                        acc[half * 4 + mt][nt][rr] + bv[nt];
                }
            }
        }
    }
}

extern "C" void kernel_launch(void* const* d_in, const int* in_sizes, int n_in,
                              void* d_out, int out_size, void* d_ws, size_t ws_size,
                              hipStream_t stream) {
    const float* x     = (const float*)d_in[0];   // [4,2048,4096]
    const float* hra_u = (const float*)d_in[1];   // [4096,8]
    const float* W     = (const float*)d_in[2];   // [4096,4096]
    const float* bias  = (const float*)d_in[3];   // [4096]
    float* out = (float*)d_out;

    char* ws = (char*)d_ws;
    float* Un = (float*)(ws);                         // 8*4096*4   = 131072 B
    float* G  = (float*)(ws + 131072);                // 64*4       = 256 B
    u16*   Wb = (u16*)(ws + 524288);                  // 4096*4096*2 = 33554432 B
    u16*   xb = (u16*)(ws + 524288 + 33554432);       // 8192*4096*2 = 67108864 B

    k_prep<<<1, 1024, 0, stream>>>(hra_u, Un, G);
    k_wy_build<<<DOUT, 256, 0, stream>>>(W, Un, G, Wb);
    k_cast_x<<<2048, 256, 0, stream>>>(x, xb);
    k_gemm<<<(MROWS / 256) * (DOUT / 256), 512, 0, stream>>>(xb, Wb, bias, out);
}